// Round 1
// 150.661 us; speedup vs baseline: 1.3030x; 1.3030x over previous
//
#include <hip/hip_runtime.h>
#include <math.h>

#define B_ 32
#define H_ 112
#define W_ 112
#define C_ 192
#define NPOS (B_*H_*W_)      // 401408
#define C4 (C_/4)            // 48
#define HALO 3
#define SW (W_ + 2*HALO)     // 118

typedef float nf4 __attribute__((ext_vector_type(4)));

// ---------------- Kernel A: per-position channel mean + max ----------------
// 4 positions per wave, 16 lanes per position, 3 float4 per lane.
// All 64 lanes load (48 B/lane); reduction is 4 butterfly stages (not 6).
__global__ __launch_bounds__(256) void reduce_kernel(const float* __restrict__ x,
                                                     float2* __restrict__ ws2) {
    const int wave = threadIdx.x >> 6;
    const int lane = threadIdx.x & 63;
    const int sub  = lane & 15;
    const int p = blockIdx.x * 16 + wave * 4 + (lane >> 4);  // grid exact: NPOS/16

    const float4* xp = (const float4*)(x + (size_t)p * C_);
    float4 v0 = xp[sub];
    float4 v1 = xp[sub + 16];
    float4 v2 = xp[sub + 32];
    float s = (v0.x + v0.y + v0.z + v0.w)
            + (v1.x + v1.y + v1.z + v1.w)
            + (v2.x + v2.y + v2.z + v2.w);
    float m = fmaxf(fmaxf(fmaxf(v0.x, v0.y), fmaxf(v0.z, v0.w)),
              fmaxf(fmaxf(fmaxf(v1.x, v1.y), fmaxf(v1.z, v1.w)),
                    fmaxf(fmaxf(v2.x, v2.y), fmaxf(v2.z, v2.w))));
    // reduce across the 16-lane group (xor offsets stay within the group)
    #pragma unroll
    for (int off = 8; off > 0; off >>= 1) {
        s += __shfl_xor(s, off);
        m = fmaxf(m, __shfl_xor(m, off));
    }
    if (sub == 0) {
        float2 r;
        r.x = s * (1.0f / (float)C_);
        r.y = m;
        ws2[p] = r;
    }
}

// ------- Kernel B: fused 7x7 conv + sigmoid + broadcast multiply -----------
// One block per (b,y) row, processed in REVERSED order so the first x reads
// hit the tail of x still resident in L3 from kernel A. x loads and out
// stores are non-temporal so dead bytes don't evict not-yet-read x.
__global__ __launch_bounds__(256) void fused_kernel(const float* __restrict__ x,
                                                    const float2* __restrict__ ws2,
                                                    const float* __restrict__ w,
                                                    float* __restrict__ out) {
    __shared__ float2 sm[7][SW];   // (avg,max) halo tile, zero-padded in x
    __shared__ float  sw[98];
    __shared__ float  satt[W_];

    const int tid = threadIdx.x;
    const int rb = (B_ * H_ - 1) - (int)blockIdx.x;   // reversed traversal
    const int b  = rb / H_;
    const int y  = rb - b * H_;

    if (tid < 98) sw[tid] = w[tid];

    // stage 7 rows x 118 cols of (avg,max), zero outside the image
    const float2* wsb = ws2 + (size_t)b * (H_ * W_);
    for (int idx = tid; idx < 7 * SW; idx += 256) {
        const int r   = idx / SW;
        const int col = idx - r * SW;
        const int yy  = y + r - HALO;
        const int xx  = col - HALO;
        float2 v = make_float2(0.0f, 0.0f);
        if (yy >= 0 && yy < H_ && xx >= 0 && xx < W_)
            v = wsb[yy * W_ + xx];
        sm[r][col] = v;
    }
    __syncthreads();

    // conv: 112 threads, no bounds checks (halo pre-zeroed)
    if (tid < W_) {
        float acc = 0.0f;
        #pragma unroll
        for (int ky = 0; ky < 7; ++ky) {
            #pragma unroll
            for (int kx = 0; kx < 7; ++kx) {
                float2 am = sm[ky][tid + kx];
                acc = fmaf(am.x, sw[(ky * 7 + kx) * 2 + 0], acc);
                acc = fmaf(am.y, sw[(ky * 7 + kx) * 2 + 1], acc);
            }
        }
        satt[tid] = 1.0f / (1.0f + __expf(-acc));
    }
    __syncthreads();

    // multiply: full row = 112*48 = 5376 float4 = 21 exact iters of 256 threads
    const size_t row4 = ((size_t)b * H_ + y) * W_ * C4;   // float4 index of row
    const nf4* xr = (const nf4*)x + row4;
    nf4* orow = (nf4*)out + row4;
    #pragma unroll
    for (int k = 0; k < (W_ * C4) / 256; ++k) {
        const int f4  = tid + k * 256;
        const int pos = f4 / C4;               // magic-mul, cheap
        nf4 v = __builtin_nontemporal_load(&xr[f4]);
        v = v * satt[pos];
        __builtin_nontemporal_store(v, &orow[f4]);
    }
}

extern "C" void kernel_launch(void* const* d_in, const int* in_sizes, int n_in,
                              void* d_out, int out_size, void* d_ws, size_t ws_size,
                              hipStream_t stream) {
    const float* x = (const float*)d_in[0];
    const float* w = (const float*)d_in[1];
    float* out = (float*)d_out;

    float2* ws2 = (float2*)d_ws;   // NPOS float2 = 3.2 MB

    // Kernel A: 16 positions per block (4 waves x 4 positions)
    reduce_kernel<<<NPOS / 16, 256, 0, stream>>>(x, ws2);

    // Kernel B: one block per (b,y) row, reversed inside the kernel
    fused_kernel<<<B_ * H_, 256, 0, stream>>>(x, ws2, w, out);
}